// Round 8
// baseline (119.268 us; speedup 1.0000x reference)
//
#include <hip/hip_runtime.h>
#include <hip/hip_bf16.h>
#include <math.h>

typedef short bf16x8 __attribute__((ext_vector_type(8)));
typedef float f32x4  __attribute__((ext_vector_type(4)));

constexpr int   H    = 256;
constexpr int   KNB  = 32;
constexpr int   CAP  = 1024;    // survivor cap (expected ~250)
constexpr int   GC   = 16;      // bin-grid cells per dim
constexpr float HINV = 1.6f;    // GC / 10.0
constexpr float HCEL = 0.625f;  // 10.0 / GC

__device__ __forceinline__ ushort f2bf(float x) {
    unsigned u = __float_as_uint(x);
    u += 0x7FFF + ((u >> 16) & 1);
    return (ushort)(u >> 16);
}

__device__ __forceinline__ float gelu_fast(float x) {
    float u = 0.7978845608028654f * (x + 0.044715f * x * x * x);
    float t = exp2f(-2.885390081777927f * u);
    return x / (1.0f + t);
}

__device__ __forceinline__ int cell_of(float x, float y, float z) {
    int cx = min(GC - 1, max(0, (int)(x * HINV)));
    int cy = min(GC - 1, max(0, (int)(y * HINV)));
    int cz = min(GC - 1, max(0, (int)(z * HINV)));
    return (cz * GC + cy) * GC + cx;
}

// ---- prep: W1t transpose (blocks 0..63); pos4 + cell histogram (rest) ----
__global__ __launch_bounds__(256)
void prep(const float* __restrict__ W1, const float* __restrict__ pos, int N,
          ushort* __restrict__ W1t, float4* __restrict__ pos4, int* __restrict__ hist) {
    const int b = blockIdx.x;
    if (b < 64) {
        __shared__ float tile[32][33];
        const int ti = b >> 3, tj = b & 7;
        const int r  = threadIdx.x >> 5, c = threadIdx.x & 31;
#pragma unroll
        for (int rr = r; rr < 32; rr += 8)
            tile[rr][c] = W1[(ti * 32 + rr) * H + tj * 32 + c];
        __syncthreads();
#pragma unroll
        for (int rr = r; rr < 32; rr += 8) {
            int j = tj * 32 + rr;
            W1t[j * H + ti * 32 + c] = f2bf(tile[c][rr]);
        }
    } else {
        int i = (b - 64) * 256 + threadIdx.x;
        if (i < N) {
            float x = pos[3 * i], y = pos[3 * i + 1], z = pos[3 * i + 2];
            pos4[i] = make_float4(x, y, z, fmaf(x, x, fmaf(y, y, z * z)));
            atomicAdd(&hist[cell_of(x, y, z)], 1);
        }
    }
}

// ---- scan: exclusive prefix over 4096 cell counts (1 block, 256 thr) ----
__global__ __launch_bounds__(256)
void scan4096(const int* __restrict__ hist, int* __restrict__ cellstart,
              int* __restrict__ cellcur, int N) {
    __shared__ int sums[256];
    const int t = threadIdx.x;
    int v[16], pre[16], run = 0;
#pragma unroll
    for (int j = 0; j < 16; j++) {
        v[j] = hist[t * 16 + j];
        pre[j] = run;
        run += v[j];
    }
    sums[t] = run;
    __syncthreads();
    for (int off = 1; off < 256; off <<= 1) {
        int x = (t >= off) ? sums[t - off] : 0;
        __syncthreads();
        sums[t] += x;
        __syncthreads();
    }
    const int base = (t == 0) ? 0 : sums[t - 1];
#pragma unroll
    for (int j = 0; j < 16; j++) {
        cellstart[t * 16 + j] = base + pre[j];
        cellcur[t * 16 + j]   = base + pre[j];
    }
    if (t == 255) cellstart[4096] = N;
}

// ---- scatter: points into cell-sorted order ----
__global__ __launch_bounds__(256)
void scatter(const float4* __restrict__ pos4, int N, int* __restrict__ cellcur,
             float4* __restrict__ pos4s, int* __restrict__ origidx) {
    int i = blockIdx.x * 256 + threadIdx.x;
    if (i < N) {
        float4 P = pos4[i];
        int c = cell_of(P.x, P.y, P.z);
        int d = atomicAdd(&cellcur[c], 1);
        pos4s[d] = P;
        origidx[d] = i;
    }
}

// ---- K2: grid-binned exact kNN; writes supE + rel features ----
__global__ __launch_bounds__(256)
void knn_select(const float4* __restrict__ pos4,
                const float4* __restrict__ pos4s,
                const int* __restrict__ origidx,
                const int* __restrict__ cellstart,
                int N, const int* __restrict__ supidx,
                float* __restrict__ featsM,    // [S][512]; cols 0..255 = supE
                float4* __restrict__ rfM)      // [S][32] = (rx,ry,rz,d)
{
    __shared__ __align__(16) float qmins[256];
    __shared__ __align__(16) float d2buf[CAP];
    __shared__ __align__(16) int   idxbuf[CAP];
    __shared__ int   sel[KNB];
    __shared__ float tau_sh;
    __shared__ int   cnt;

    const int s = blockIdx.x;
    const int t = threadIdx.x;

    const int sidx = supidx[s];
    const float4 sp = pos4[sidx];
    const float sx = sp.x, sy = sp.y, sz = sp.z;
    const float c0 = -2.f * sx, c1 = -2.f * sy, c2 = -2.f * sz;

    constexpr float L2_10000 = 13.287712379549449f;

    // supernode abs-pos embed -> featsM[s][0..255]
    {
        float se = 0.f;
        if (t < 252) {
            int c  = t / 84;
            int rr = t - c * 84;
            int f  = (rr < 42) ? rr : rr - 42;
            float coord = (c == 0) ? sx : ((c == 1) ? sy : sz);
            float ang = coord * exp2f(-(float)f * (L2_10000 / 42.f));
            se = (rr < 42) ? __sinf(ang) : __cosf(ang);
        }
        featsM[s * (2 * H) + t] = se;
    }
    if (t == 0) cnt = 0;

    // sample 8192 original-order (spatially random) points; 32 per thread
    {
        float mn = INFINITY;
#pragma unroll
        for (int n = 0; n < 8; n++) {
            int i = n * 1024 + 4 * t;
            if (i + 3 < N) {
#pragma unroll
                for (int u = 0; u < 4; u++) {
                    float4 P = pos4[i + u];
                    float q = fmaf(P.x, c0, fmaf(P.y, c1, fmaf(P.z, c2, P.w)));
                    mn = fminf(mn, q);
                }
            }
        }
        qmins[t] = mn;
    }
    __syncthreads();
    // 32nd-smallest of 256 disjoint-group minima => >=32 points have q <= tau
    {
        float my = qmins[t];
        int lt = 0, le = 0;
        for (int u = 0; u < 256; u += 4) {
            float4 v = *(const float4*)&qmins[u];
            lt += (v.x < my) + (v.y < my) + (v.z < my) + (v.w < my);
            le += (v.x <= my) + (v.y <= my) + (v.z <= my) + (v.w <= my);
        }
        if (lt <= 31 && le > 31) tau_sh = my;
    }
    __syncthreads();

    // ball radius: d2 = q + |s|^2; margin absorbs fp32 cancellation
    const float R2 = tau_sh + sp.w + 1e-3f;
    const float R  = sqrtf(fmaxf(R2, 0.f));

    const int x0 = max(0, (int)floorf((sx - R) * HINV));
    const int x1 = min(GC - 1, (int)floorf((sx + R) * HINV));
    const int y0 = max(0, (int)floorf((sy - R) * HINV));
    const int y1 = min(GC - 1, (int)floorf((sy + R) * HINV));
    const int z0 = max(0, (int)floorf((sz - R) * HINV));
    const int z1 = min(GC - 1, (int)floorf((sz + R) * HINV));
    const int nx = x1 - x0 + 1, ny = y1 - y0 + 1, nz = z1 - z0 + 1;
    const int ncells = nx * ny * nz;

    // gather candidates from cells intersecting the ball
    for (int ci = t; ci < ncells; ci += 256) {
        int cx = ci % nx, rem = ci / nx;
        int cy = rem % ny, cz = rem / ny;
        int X = x0 + cx, Y = y0 + cy, Z = z0 + cz;
        // ball-box cull
        float lx = X * HCEL, ly = Y * HCEL, lz = Z * HCEL;
        float ddx = fmaxf(fmaxf(lx - sx, sx - (lx + HCEL)), 0.f);
        float ddy = fmaxf(fmaxf(ly - sy, sy - (ly + HCEL)), 0.f);
        float ddz = fmaxf(fmaxf(lz - sz, sz - (lz + HCEL)), 0.f);
        if (ddx * ddx + ddy * ddy + ddz * ddz > R2) continue;
        int cell = (Z * GC + Y) * GC + X;
        int b0 = cellstart[cell], b1 = cellstart[cell + 1];
        for (int u = b0; u < b1; u++) {
            float4 P = pos4s[u];
            float dx = sx - P.x, dy = sy - P.y, dz = sz - P.z;
            float d2 = dx * dx + dy * dy + dz * dz;
            if (d2 <= R2) {
                int sl = atomicAdd(&cnt, 1);
                if (sl < CAP) { d2buf[sl] = d2; idxbuf[sl] = origidx[u]; }
            }
        }
    }
    __syncthreads();
    const int M = min(cnt, CAP);
    const int Mpad = (M + 3) & ~3;
    for (int u = M + t; u < Mpad; u += 256) { d2buf[u] = INFINITY; idxbuf[u] = 0x7fffffff; }
    __syncthreads();

    // exact rank-merge -> top-32 (tie-break: smaller original index)
    for (int u = t; u < M; u += 256) {
        float my  = d2buf[u];
        int   myi = idxbuf[u];
        int rank = 0;
        for (int v = 0; v < Mpad; v += 4) {
            float4 dv = *(const float4*)&d2buf[v];
            int4   iv = *(const int4*)&idxbuf[v];
            rank += (dv.x < my) || (dv.x == my && iv.x < myi);
            rank += (dv.y < my) || (dv.y == my && iv.y < myi);
            rank += (dv.z < my) || (dv.z == my && iv.z < myi);
            rank += (dv.w < my) || (dv.w == my && iv.w < myi);
        }
        if (rank < KNB) sel[rank] = myi;
    }
    __syncthreads();

    if (t < KNB) {
        int ni = sel[t];
        float4 P = pos4[ni];
        float rx = sx - P.x, ry = sy - P.y, rz = sz - P.z;
        float dd = sqrtf(rx * rx + ry * ry + rz * rz);
        rfM[s * KNB + t] = make_float4(rx, ry, rz, dd);
    }
}

// ---- K3: sincos embed + MFMA GEMM1 + gelu + mean_k -> hbM ----
__global__ __launch_bounds__(512, 4)
void embed_gemm1(const float4* __restrict__ rfM,
                 const ushort* __restrict__ W1t, const float* __restrict__ b1,
                 float* __restrict__ hbM)
{
    __shared__ ushort msg[KNB * H];   // 16 KB bf16 msg[k][i], XOR-swizzled rows
    __shared__ float  rf[KNB][5];

    const int s    = blockIdx.x;
    const int t    = threadIdx.x;
    const int lane = t & 63;
    const int w    = t >> 6;

    constexpr float L2_10000 = 13.287712379549449f;

    if (t < KNB) {
        float4 v = rfM[s * KNB + t];
        rf[t][0] = v.x; rf[t][1] = v.y; rf[t][2] = v.z; rf[t][3] = v.w;
    }
    __syncthreads();

#pragma unroll
    for (int n = 0; n < 8; n++) {
        int item = t + n * 512;
        int f = item & 31;
        int c = (item >> 5) & 3;
        int k = item >> 7;
        float ang = rf[k][c] * exp2f(-(float)f * (L2_10000 / 32.f));
        int swz = (k & 7) << 3;
        msg[((k << 8) | (c * 64 + f))      ^ swz] = f2bf(__sinf(ang));
        msg[((k << 8) | (c * 64 + 32 + f)) ^ swz] = f2bf(__cosf(ang));
    }
    __syncthreads();

    {
        const int lr = lane & 15;
        const int lg = lane >> 4;
        f32x4 acc00 = {0,0,0,0}, acc01 = {0,0,0,0};
        f32x4 acc10 = {0,0,0,0}, acc11 = {0,0,0,0};
#pragma unroll
        for (int kk = 0; kk < 8; kk++) {
            const int i0 = kk * 32 + lg * 8;
            bf16x8 a0 = *(const bf16x8*)(W1t + ((32 * w      + lr) << 8) + i0);
            bf16x8 a1 = *(const bf16x8*)(W1t + ((32 * w + 16 + lr) << 8) + i0);
            const int swz = (lr & 7) << 3;
            bf16x8 b0  = *(const bf16x8*)(msg + ((( lr       << 8) | i0) ^ swz));
            bf16x8 b1v = *(const bf16x8*)(msg + ((((lr + 16) << 8) | i0) ^ swz));
            acc00 = __builtin_amdgcn_mfma_f32_16x16x32_bf16(a0, b0, acc00, 0, 0, 0);
            acc01 = __builtin_amdgcn_mfma_f32_16x16x32_bf16(a0, b1v, acc01, 0, 0, 0);
            acc10 = __builtin_amdgcn_mfma_f32_16x16x32_bf16(a1, b0, acc10, 0, 0, 0);
            acc11 = __builtin_amdgcn_mfma_f32_16x16x32_bf16(a1, b1v, acc11, 0, 0, 0);
        }
        float part[8];
#pragma unroll
        for (int m = 0; m < 2; m++)
#pragma unroll
            for (int r = 0; r < 4; r++) {
                int j = 32 * w + 16 * m + 4 * lg + r;
                float bj = b1[j];
                float h0 = (m == 0 ? acc00[r] : acc10[r]) + bj;
                float h1 = (m == 0 ? acc01[r] : acc11[r]) + bj;
                part[m * 4 + r] = gelu_fast(h0) + gelu_fast(h1);
            }
#pragma unroll
        for (int off = 1; off < 16; off <<= 1)
#pragma unroll
            for (int u = 0; u < 8; u++)
                part[u] += __shfl_xor(part[u], off);
        if (lr == 0) {
#pragma unroll
            for (int u = 0; u < 8; u++) {
                int m = u >> 2, r = u & 3;
                hbM[s * H + 32 * w + 16 * m + 4 * lg + r] = part[u] * (1.0f / 32.0f);
            }
        }
    }
}

// ---- kernel B: C[M x N] = A[M x K] @ B[K x N] + bias, fp32 tiled 32x32 ----
__global__ __launch_bounds__(256)
void gemm_bias(const float* __restrict__ A, const float* __restrict__ B,
               const float* __restrict__ bias, float* __restrict__ C,
               int K, int N, int ldc)
{
    __shared__ float As[32][36];
    __shared__ float Bs[32][36];
    const int t  = threadIdx.x;
    const int bm = blockIdx.x, bn = blockIdx.y;
    const int tx = t & 15, ty = t >> 4;
    const int lr = t >> 3, lc = (t & 7) * 4;

    float acc[2][2] = {{0.f, 0.f}, {0.f, 0.f}};

    for (int kk = 0; kk < K; kk += 32) {
        float4 av = *(const float4*)&A[(bm * 32 + lr) * K + kk + lc];
        float4 bv = *(const float4*)&B[(kk + lr) * N + bn * 32 + lc];
        *(float4*)&As[lr][lc] = av;
        *(float4*)&Bs[lr][lc] = bv;
        __syncthreads();
#pragma unroll
        for (int k = 0; k < 32; k++) {
            float a0 = As[2 * ty][k], a1 = As[2 * ty + 1][k];
            float2 b01 = *(const float2*)&Bs[k][2 * tx];
            acc[0][0] += a0 * b01.x; acc[0][1] += a0 * b01.y;
            acc[1][0] += a1 * b01.x; acc[1][1] += a1 * b01.y;
        }
        __syncthreads();
    }
#pragma unroll
    for (int u = 0; u < 2; u++) {
        int row = bm * 32 + 2 * ty + u;
        int col = bn * 32 + 2 * tx;
        C[row * ldc + col]     = acc[u][0] + bias[col];
        C[row * ldc + col + 1] = acc[u][1] + bias[col + 1];
    }
}

extern "C" void kernel_launch(void* const* d_in, const int* in_sizes, int n_in,
                              void* d_out, int out_size, void* d_ws, size_t ws_size,
                              hipStream_t stream) {
    const float* pos = (const float*)d_in[0];
    const int*   sup = (const int*)d_in[1];
    const float* W1  = (const float*)d_in[2];
    const float* b1  = (const float*)d_in[3];
    const float* W2  = (const float*)d_in[4];
    const float* b2  = (const float*)d_in[5];
    const float* Wp  = (const float*)d_in[6];
    const float* bp  = (const float*)d_in[7];

    const int N = in_sizes[0] / 3;
    const int S = in_sizes[1];
    float* out = (float*)d_out;

    char* ws = (char*)d_ws;
    ushort* W1t       = (ushort*)ws;                       // 128 KB
    float4* pos4      = (float4*)(ws + (128 << 10));       // 800 KB
    float4* pos4s     = (float4*)(ws + (960 << 10));       // 800 KB (cell-sorted)
    int*    origidx   = (int*)(ws + (1792 << 10));         // 200 KB
    int*    hist      = (int*)(ws + (2000 << 10));         // 16 KB
    int*    cellstart = (int*)(ws + (2016 << 10));         // 16.4 KB
    int*    cellcur   = (int*)(ws + (2036 << 10));         // 16 KB
    float*  hbM       = (float*)(ws + (2052 << 10));       // 1 MB
    float*  featsM    = (float*)(ws + (3076 << 10));       // 2 MB
    float4* rfM       = (float4*)(ws + (5124 << 10));      // 512 KB

    hipMemsetAsync(hist, 0, 4096 * sizeof(int), stream);
    prep<<<64 + (N + 255) / 256, 256, 0, stream>>>(W1, pos, N, W1t, pos4, hist);
    scan4096<<<1, 256, 0, stream>>>(hist, cellstart, cellcur, N);
    scatter<<<(N + 255) / 256, 256, 0, stream>>>(pos4, N, cellcur, pos4s, origidx);
    knn_select<<<S, 256, 0, stream>>>(pos4, pos4s, origidx, cellstart, N, sup,
                                      featsM, rfM);
    embed_gemm1<<<S, 512, 0, stream>>>(rfM, W1t, b1, hbM);
    gemm_bias<<<dim3(S / 32, H / 32), 256, 0, stream>>>(hbM, W2, b2, featsM + H,
                                                        H, H, 2 * H);
    gemm_bias<<<dim3(S / 32, H / 32), 256, 0, stream>>>(featsM, Wp, bp, out,
                                                        2 * H, H, H);
}

// Round 9
// 103.660 us; speedup vs baseline: 1.1506x; 1.1506x over previous
//
#include <hip/hip_runtime.h>
#include <hip/hip_bf16.h>
#include <math.h>

typedef short bf16x8 __attribute__((ext_vector_type(8)));
typedef float f32x4  __attribute__((ext_vector_type(4)));

constexpr int   H    = 256;
constexpr int   KNB  = 32;
constexpr int   CAP  = 1024;    // survivor cap (expected ~280)
constexpr int   GC   = 16;      // bin-grid cells per dim
constexpr float HINV = 1.6f;    // GC / 10.0
constexpr float HCEL = 0.625f;  // 10.0 / GC

__device__ __forceinline__ ushort f2bf(float x) {
    unsigned u = __float_as_uint(x);
    u += 0x7FFF + ((u >> 16) & 1);
    return (ushort)(u >> 16);
}

__device__ __forceinline__ float gelu_fast(float x) {
    float u = 0.7978845608028654f * (x + 0.044715f * x * x * x);
    float t = exp2f(-2.885390081777927f * u);
    return x / (1.0f + t);
}

__device__ __forceinline__ int cell_of(float x, float y, float z) {
    int cx = min(GC - 1, max(0, (int)(x * HINV)));
    int cy = min(GC - 1, max(0, (int)(y * HINV)));
    int cz = min(GC - 1, max(0, (int)(z * HINV)));
    return (cz * GC + cy) * GC + cx;
}

// ---- prep: W1t transpose (blocks 0..63); pos4 + cell histogram (rest) ----
__global__ __launch_bounds__(256)
void prep(const float* __restrict__ W1, const float* __restrict__ pos, int N,
          ushort* __restrict__ W1t, float4* __restrict__ pos4, int* __restrict__ hist) {
    const int b = blockIdx.x;
    if (b < 64) {
        __shared__ float tile[32][33];
        const int ti = b >> 3, tj = b & 7;
        const int r  = threadIdx.x >> 5, c = threadIdx.x & 31;
#pragma unroll
        for (int rr = r; rr < 32; rr += 8)
            tile[rr][c] = W1[(ti * 32 + rr) * H + tj * 32 + c];
        __syncthreads();
#pragma unroll
        for (int rr = r; rr < 32; rr += 8) {
            int j = tj * 32 + rr;
            W1t[j * H + ti * 32 + c] = f2bf(tile[c][rr]);
        }
    } else {
        int i = (b - 64) * 256 + threadIdx.x;
        if (i < N) {
            float x = pos[3 * i], y = pos[3 * i + 1], z = pos[3 * i + 2];
            pos4[i] = make_float4(x, y, z, fmaf(x, x, fmaf(y, y, z * z)));
            atomicAdd(&hist[cell_of(x, y, z)], 1);
        }
    }
}

// ---- scan: exclusive prefix over 4096 cell counts (1 block, 256 thr) ----
__global__ __launch_bounds__(256)
void scan4096(const int* __restrict__ hist, int* __restrict__ cellstart,
              int* __restrict__ cellcur, int N) {
    __shared__ int sums[256];
    const int t = threadIdx.x;
    int v[16], pre[16], run = 0;
#pragma unroll
    for (int j = 0; j < 16; j++) {
        v[j] = hist[t * 16 + j];
        pre[j] = run;
        run += v[j];
    }
    sums[t] = run;
    __syncthreads();
    for (int off = 1; off < 256; off <<= 1) {
        int x = (t >= off) ? sums[t - off] : 0;
        __syncthreads();
        sums[t] += x;
        __syncthreads();
    }
    const int base = (t == 0) ? 0 : sums[t - 1];
#pragma unroll
    for (int j = 0; j < 16; j++) {
        cellstart[t * 16 + j] = base + pre[j];
        cellcur[t * 16 + j]   = base + pre[j];
    }
    if (t == 255) cellstart[4096] = N;
}

// ---- scatter: points into cell-sorted order ----
__global__ __launch_bounds__(256)
void scatter(const float4* __restrict__ pos4, int N, int* __restrict__ cellcur,
             float4* __restrict__ pos4s, int* __restrict__ origidx) {
    int i = blockIdx.x * 256 + threadIdx.x;
    if (i < N) {
        float4 P = pos4[i];
        int c = cell_of(P.x, P.y, P.z);
        int d = atomicAdd(&cellcur[c], 1);
        pos4s[d] = P;
        origidx[d] = i;
    }
}

// ---- fused: cell-count tau -> balanced gather -> exact top-32 -> embed ->
//      MFMA GEMM1 -> gelu/mean -> W2 matvec; writes featsM[s][0:512] ----
__global__ __launch_bounds__(256, 4)
void fused_knn_mlp(const float4* __restrict__ pos4,
                   const float4* __restrict__ pos4s,
                   const int* __restrict__ origidx,
                   const int* __restrict__ cellstart,
                   const int* __restrict__ supidx,
                   const ushort* __restrict__ W1t, const float* __restrict__ b1,
                   const float* __restrict__ W2, const float* __restrict__ b2,
                   float* __restrict__ featsM)
{
    // 16 KB pool, time-multiplexed:
    //  select: amaxd[128]@0 | acnt[128]@512 | cb0[256]@1024 | ccn[256]@2048 |
    //          cpre[256]@3072 | d2buf[1024]@4096 | idxbuf[1024]@8192
    //  mlp:    msg bf16[32][256]@0 (16 KB, XOR-swizzled)   then p2 f32[1024]@0
    __shared__ __align__(16) char pool[16384];
    float*  amaxd  = (float*)pool;
    int*    acnt   = (int*)(pool + 512);
    int*    cb0    = (int*)(pool + 1024);
    int*    ccn    = (int*)(pool + 2048);
    int*    cpre   = (int*)(pool + 3072);
    float*  d2buf  = (float*)(pool + 4096);
    int*    idxbuf = (int*)(pool + 8192);
    ushort* msg    = (ushort*)pool;
    float*  p2     = (float*)pool;

    __shared__ float rf[KNB][5];
    __shared__ int   sel[KNB];
    __shared__ float hb[H];
    __shared__ float tau2_sh;
    __shared__ int   cnt, ncl;

    const int s    = blockIdx.x;
    const int t    = threadIdx.x;
    const int lane = t & 63;
    const int w    = t >> 6;

    const int sidx = supidx[s];
    const float4 sp = pos4[sidx];
    const float sx = sp.x, sy = sp.y, sz = sp.z;

    constexpr float L2_10000 = 13.287712379549449f;

    // supernode abs-pos embed -> featsM[s][0..255]
    {
        float se = 0.f;
        if (t < 252) {
            int c  = t / 84;
            int rr = t - c * 84;
            int f  = (rr < 42) ? rr : rr - 42;
            float coord = (c == 0) ? sx : ((c == 1) ? sy : sz);
            float ang = coord * exp2f(-(float)f * (L2_10000 / 42.f));
            se = (rr < 42) ? __sinf(ang) : __cosf(ang);
        }
        featsM[s * (2 * H) + t] = se;
    }
    if (t == 0) { cnt = 0; ncl = 0; tau2_sh = 301.f; }

    // ---- stage A: tau^2 from C_2 cell counts (no point loads) ----
    const int scx = min(GC - 1, max(0, (int)(sx * HINV)));
    const int scy = min(GC - 1, max(0, (int)(sy * HINV)));
    const int scz = min(GC - 1, max(0, (int)(sz * HINV)));
    const int ax0 = max(0, scx - 2), ax1 = min(GC - 1, scx + 2);
    const int ay0 = max(0, scy - 2), ay1 = min(GC - 1, scy + 2);
    const int az0 = max(0, scz - 2), az1 = min(GC - 1, scz + 2);
    const int anx = ax1 - ax0 + 1, any_ = ay1 - ay0 + 1, anz = az1 - az0 + 1;
    const int an  = anx * any_ * anz;    // <= 125
    __syncthreads();
    for (int ci = t; ci < an; ci += 256) {
        int X = ax0 + ci % anx, rem = ci / anx;
        int Y = ay0 + rem % any_, Z = az0 + rem / any_;
        int cell = (Z * GC + Y) * GC + X;
        acnt[ci] = cellstart[cell + 1] - cellstart[cell];
        float lx = X * HCEL, ly = Y * HCEL, lz = Z * HCEL;
        float mx = fmaxf(fabsf(sx - lx), fabsf(lx + HCEL - sx));
        float my = fmaxf(fabsf(sy - ly), fabsf(ly + HCEL - sy));
        float mz = fmaxf(fabsf(sz - lz), fabsf(lz + HCEL - sz));
        amaxd[ci] = mx * mx + my * my + mz * mz;   // upper bound on d2 of any pt in cell
    }
    __syncthreads();
    // smallest maxdist2 whose cumulative count reaches 32 => >=32 pts within tau
    for (int ci = t; ci < an; ci += 256) {
        float myv = amaxd[ci];
        int S = 0;
        for (int j = 0; j < an; j++) {
            bool less = (amaxd[j] < myv) || (amaxd[j] == myv && j < ci);
            S += less ? acnt[j] : 0;
        }
        if (S < KNB && KNB <= S + acnt[ci]) tau2_sh = myv;
    }
    __syncthreads();
    const float R2 = tau2_sh + 1e-3f;
    const float R  = sqrtf(R2);

    // ---- stage B: enumerate ball cells, build balanced candidate list ----
    const int bx0 = max(0, (int)floorf((sx - R) * HINV));
    const int bx1 = min(GC - 1, (int)floorf((sx + R) * HINV));
    const int by0 = max(0, (int)floorf((sy - R) * HINV));
    const int by1 = min(GC - 1, (int)floorf((sy + R) * HINV));
    const int bz0 = max(0, (int)floorf((sz - R) * HINV));
    const int bz1 = min(GC - 1, (int)floorf((sz + R) * HINV));
    const int nbx = bx1 - bx0 + 1, nby = by1 - by0 + 1, nbz = bz1 - bz0 + 1;
    const int ncb = nbx * nby * nbz;
    for (int ci = t; ci < ncb; ci += 256) {
        int X = bx0 + ci % nbx, rem = ci / nbx;
        int Y = by0 + rem % nby, Z = bz0 + rem / nby;
        float lx = X * HCEL, ly = Y * HCEL, lz = Z * HCEL;
        float ddx = fmaxf(fmaxf(lx - sx, sx - (lx + HCEL)), 0.f);
        float ddy = fmaxf(fmaxf(ly - sy, sy - (ly + HCEL)), 0.f);
        float ddz = fmaxf(fmaxf(lz - sz, sz - (lz + HCEL)), 0.f);
        if (ddx * ddx + ddy * ddy + ddz * ddz > R2) continue;
        int cell = (Z * GC + Y) * GC + X;
        int b0v = cellstart[cell], b1v = cellstart[cell + 1];
        if (b1v > b0v) {
            int sl = atomicAdd(&ncl, 1);
            if (sl < 256) { cb0[sl] = b0v; ccn[sl] = b1v - b0v; }
        }
    }
    __syncthreads();
    const int nclc = min(ncl, 256);
    {   // inclusive prefix sum over 256 (Hillis-Steele)
        int v = (t < nclc) ? ccn[t] : 0;
        cpre[t] = v;
        __syncthreads();
        for (int off = 1; off < 256; off <<= 1) {
            int x = (t >= off) ? cpre[t - off] : 0;
            __syncthreads();
            cpre[t] += x;
            __syncthreads();
        }
    }
    const int tot = cpre[255];

    // balanced candidate walk; wave-aggregated LDS append of survivors
    for (int j0 = 0; j0 < tot; j0 += 256) {
        int j = j0 + t;
        bool pass = false;
        float pd2 = 0.f;
        int pidx = 0;
        if (j < tot) {
            int lo = 0;
#pragma unroll
            for (int st = 128; st; st >>= 1)
                if (lo + st <= 256 && cpre[lo + st - 1] <= j) lo += st;
            int u = cb0[lo] + (j - (cpre[lo] - ccn[lo]));
            float4 P = pos4s[u];
            float dx = sx - P.x, dy = sy - P.y, dz = sz - P.z;
            pd2 = dx * dx + dy * dy + dz * dz;
            if (pd2 <= R2) { pass = true; pidx = origidx[u]; }
        }
        unsigned long long m = __ballot(pass);
        if (m) {
            int ldr = __ffsll(m) - 1;
            int base = 0;
            if (lane == ldr) base = atomicAdd(&cnt, __popcll(m));
            base = __shfl(base, ldr);
            if (pass) {
                int slp = base + __popcll(m & ((1ull << lane) - 1ull));
                if (slp < CAP) { d2buf[slp] = pd2; idxbuf[slp] = pidx; }
            }
        }
    }
    __syncthreads();
    const int M = min(cnt, CAP);
    const int Mpad = (M + 3) & ~3;
    for (int u = M + t; u < Mpad; u += 256) { d2buf[u] = INFINITY; idxbuf[u] = 0x7fffffff; }
    __syncthreads();

    // exact rank-merge -> top-32 (tie-break: smaller original index)
    for (int u = t; u < M; u += 256) {
        float myv = d2buf[u];
        int   myi = idxbuf[u];
        int rank = 0;
        for (int v = 0; v < Mpad; v += 4) {
            float4 dv = *(const float4*)&d2buf[v];
            int4   iv = *(const int4*)&idxbuf[v];
            rank += (dv.x < myv) || (dv.x == myv && iv.x < myi);
            rank += (dv.y < myv) || (dv.y == myv && iv.y < myi);
            rank += (dv.z < myv) || (dv.z == myv && iv.z < myi);
            rank += (dv.w < myv) || (dv.w == myv && iv.w < myi);
        }
        if (rank < KNB) sel[rank] = myi;
    }
    __syncthreads();
    if (t < KNB) {
        int ni = sel[t];
        float4 P = pos4[ni];
        float rx = sx - P.x, ry = sy - P.y, rz = sz - P.z;
        float dd = sqrtf(rx * rx + ry * ry + rz * rz);
        rf[t][0] = rx; rf[t][1] = ry; rf[t][2] = rz; rf[t][3] = dd;
    }
    __syncthreads();   // pool select-stage dead; msg takes over

    // ---- sincos embed -> msg[k][i] bf16, row-XOR swizzle ----
#pragma unroll
    for (int n = 0; n < 16; n++) {
        int item = t + n * 256;
        int f = item & 31;
        int c = (item >> 5) & 3;
        int k = item >> 7;
        float ang = rf[k][c] * exp2f(-(float)f * (L2_10000 / 32.f));
        int swz = (k & 7) << 3;
        msg[((k << 8) | (c * 64 + f))      ^ swz] = f2bf(__sinf(ang));
        msg[((k << 8) | (c * 64 + 32 + f)) ^ swz] = f2bf(__cosf(ang));
    }
    __syncthreads();

    // ---- MFMA GEMM1: wave w owns j-rows [64w, 64w+64) (4 M-tiles x 2 N-tiles) ----
    {
        const int lr = lane & 15;
        const int lg = lane >> 4;
        f32x4 acc[4][2];
#pragma unroll
        for (int mt = 0; mt < 4; mt++)
#pragma unroll
            for (int nt = 0; nt < 2; nt++) acc[mt][nt] = (f32x4){0, 0, 0, 0};
#pragma unroll
        for (int kk = 0; kk < 8; kk++) {
            const int i0 = kk * 32 + lg * 8;
            const int swz = (lr & 7) << 3;
            bf16x8 b0  = *(const bf16x8*)(msg + ((( lr       << 8) | i0) ^ swz));
            bf16x8 b1v = *(const bf16x8*)(msg + ((((lr + 16) << 8) | i0) ^ swz));
#pragma unroll
            for (int mt = 0; mt < 4; mt++) {
                bf16x8 a = *(const bf16x8*)(W1t + ((64 * w + 16 * mt + lr) << 8) + i0);
                acc[mt][0] = __builtin_amdgcn_mfma_f32_16x16x32_bf16(a, b0,  acc[mt][0], 0, 0, 0);
                acc[mt][1] = __builtin_amdgcn_mfma_f32_16x16x32_bf16(a, b1v, acc[mt][1], 0, 0, 0);
            }
        }
        float part[16];
#pragma unroll
        for (int mt = 0; mt < 4; mt++)
#pragma unroll
            for (int r = 0; r < 4; r++) {
                int j = 64 * w + 16 * mt + 4 * lg + r;
                float bj = b1[j];
                part[mt * 4 + r] = gelu_fast(acc[mt][0][r] + bj) + gelu_fast(acc[mt][1][r] + bj);
            }
#pragma unroll
        for (int off = 1; off < 16; off <<= 1)
#pragma unroll
            for (int u = 0; u < 16; u++)
                part[u] += __shfl_xor(part[u], off);
        if (lr == 0) {
#pragma unroll
            for (int u = 0; u < 16; u++) {
                int mt = u >> 2, r = u & 3;
                hb[64 * w + 16 * mt + 4 * lg + r] = part[u] * (1.0f / 32.0f);
            }
        }
    }
    __syncthreads();   // hb complete; msg dead -> p2 takes pool

    // ---- W2 matvec: agg = hb @ W2 + b2 -> featsM[s][256..511] ----
    {
        const int g  = t >> 6;
        const int j4 = (t & 63) * 4;
        const int ib = g * 64;
        float4 a = {0.f, 0.f, 0.f, 0.f};
        for (int i = 0; i < 64; i++) {
            float hv = hb[ib + i];
            float4 wv = *(const float4*)&W2[(ib + i) * H + j4];
            a.x = fmaf(hv, wv.x, a.x); a.y = fmaf(hv, wv.y, a.y);
            a.z = fmaf(hv, wv.z, a.z); a.w = fmaf(hv, wv.w, a.w);
        }
        *(float4*)&p2[g * 256 + j4] = a;
    }
    __syncthreads();
    {
        float agg = p2[t] + p2[256 + t] + p2[512 + t] + p2[768 + t] + b2[t];
        featsM[s * (2 * H) + H + t] = agg;
    }
}

// ---- kernel B: C[M x N] = A[M x K] @ B[K x N] + bias, fp32 tiled 32x32 ----
__global__ __launch_bounds__(256)
void gemm_bias(const float* __restrict__ A, const float* __restrict__ B,
               const float* __restrict__ bias, float* __restrict__ C,
               int K, int N, int ldc)
{
    __shared__ float As[32][36];
    __shared__ float Bs[32][36];
    const int t  = threadIdx.x;
    const int bm = blockIdx.x, bn = blockIdx.y;
    const int tx = t & 15, ty = t >> 4;
    const int lr = t >> 3, lc = (t & 7) * 4;

    float acc[2][2] = {{0.f, 0.f}, {0.f, 0.f}};

    for (int kk = 0; kk < K; kk += 32) {
        float4 av = *(const float4*)&A[(bm * 32 + lr) * K + kk + lc];
        float4 bv = *(const float4*)&B[(kk + lr) * N + bn * 32 + lc];
        *(float4*)&As[lr][lc] = av;
        *(float4*)&Bs[lr][lc] = bv;
        __syncthreads();
#pragma unroll
        for (int k = 0; k < 32; k++) {
            float a0 = As[2 * ty][k], a1 = As[2 * ty + 1][k];
            float2 b01 = *(const float2*)&Bs[k][2 * tx];
            acc[0][0] += a0 * b01.x; acc[0][1] += a0 * b01.y;
            acc[1][0] += a1 * b01.x; acc[1][1] += a1 * b01.y;
        }
        __syncthreads();
    }
#pragma unroll
    for (int u = 0; u < 2; u++) {
        int row = bm * 32 + 2 * ty + u;
        int col = bn * 32 + 2 * tx;
        C[row * ldc + col]     = acc[u][0] + bias[col];
        C[row * ldc + col + 1] = acc[u][1] + bias[col + 1];
    }
}

extern "C" void kernel_launch(void* const* d_in, const int* in_sizes, int n_in,
                              void* d_out, int out_size, void* d_ws, size_t ws_size,
                              hipStream_t stream) {
    const float* pos = (const float*)d_in[0];
    const int*   sup = (const int*)d_in[1];
    const float* W1  = (const float*)d_in[2];
    const float* b1  = (const float*)d_in[3];
    const float* W2  = (const float*)d_in[4];
    const float* b2  = (const float*)d_in[5];
    const float* Wp  = (const float*)d_in[6];
    const float* bp  = (const float*)d_in[7];

    const int N = in_sizes[0] / 3;
    const int S = in_sizes[1];
    float* out = (float*)d_out;

    char* ws = (char*)d_ws;
    ushort* W1t       = (ushort*)ws;                       // 128 KB
    float4* pos4      = (float4*)(ws + (128 << 10));       // 800 KB
    float4* pos4s     = (float4*)(ws + (960 << 10));       // 800 KB (cell-sorted)
    int*    origidx   = (int*)(ws + (1792 << 10));         // 200 KB
    int*    hist      = (int*)(ws + (2000 << 10));         // 16 KB
    int*    cellstart = (int*)(ws + (2016 << 10));         // 16.4 KB
    int*    cellcur   = (int*)(ws + (2036 << 10));         // 16 KB
    float*  featsM    = (float*)(ws + (2052 << 10));       // 2 MB

    hipMemsetAsync(hist, 0, 4096 * sizeof(int), stream);
    prep<<<64 + (N + 255) / 256, 256, 0, stream>>>(W1, pos, N, W1t, pos4, hist);
    scan4096<<<1, 256, 0, stream>>>(hist, cellstart, cellcur, N);
    scatter<<<(N + 255) / 256, 256, 0, stream>>>(pos4, N, cellcur, pos4s, origidx);
    fused_knn_mlp<<<S, 256, 0, stream>>>(pos4, pos4s, origidx, cellstart, sup,
                                         W1t, b1, W2, b2, featsM);
    gemm_bias<<<dim3(S / 32, H / 32), 256, 0, stream>>>(featsM, Wp, bp, out,
                                                        2 * H, H, H);
}

// Round 10
// 93.629 us; speedup vs baseline: 1.2738x; 1.1071x over previous
//
#include <hip/hip_runtime.h>
#include <hip/hip_bf16.h>
#include <math.h>

typedef short bf16x8 __attribute__((ext_vector_type(8)));
typedef float f32x4  __attribute__((ext_vector_type(4)));

constexpr int   H     = 256;
constexpr int   KNB   = 32;
constexpr int   GC    = 16;      // bin-grid cells per dim
constexpr float HINV  = 1.6f;    // GC / 10.0
constexpr float HCEL  = 0.625f;  // 10.0 / GC
constexpr int   SLOTS = 32;      // slots per cell (avg fill ~12.2; overflow spills)
constexpr int   OCAP  = 256;     // overflow list capacity
constexpr int   CAP   = 512;     // candidate buffer

__device__ __forceinline__ ushort f2bf(float x) {
    unsigned u = __float_as_uint(x);
    u += 0x7FFF + ((u >> 16) & 1);
    return (ushort)(u >> 16);
}

__device__ __forceinline__ float gelu_fast(float x) {
    float u = 0.7978845608028654f * (x + 0.044715f * x * x * x);
    float t = exp2f(-2.885390081777927f * u);
    return x / (1.0f + t);
}

__device__ __forceinline__ int cell_of(float x, float y, float z) {
    int cx = min(GC - 1, max(0, (int)(x * HINV)));
    int cy = min(GC - 1, max(0, (int)(y * HINV)));
    int cz = min(GC - 1, max(0, (int)(z * HINV)));
    return (cz * GC + cy) * GC + cx;
}

// ---- prep: W1t transpose (blocks 0..63); slotted scatter (rest) ----
__global__ __launch_bounds__(256)
void prep(const float* __restrict__ W1, const float* __restrict__ pos, int N,
          ushort* __restrict__ W1t, float4* __restrict__ pos4s,
          int* __restrict__ origidx, int* __restrict__ cellcnt,
          int* __restrict__ ovfidx, float4* __restrict__ ovfpos) {
    const int b = blockIdx.x;
    if (b < 64) {
        __shared__ float tile[32][33];
        const int ti = b >> 3, tj = b & 7;
        const int r  = threadIdx.x >> 5, c = threadIdx.x & 31;
#pragma unroll
        for (int rr = r; rr < 32; rr += 8)
            tile[rr][c] = W1[(ti * 32 + rr) * H + tj * 32 + c];
        __syncthreads();
#pragma unroll
        for (int rr = r; rr < 32; rr += 8) {
            int j = tj * 32 + rr;
            W1t[j * H + ti * 32 + c] = f2bf(tile[c][rr]);
        }
    } else {
        int i = (b - 64) * 256 + threadIdx.x;
        if (i < N) {
            float x = pos[3 * i], y = pos[3 * i + 1], z = pos[3 * i + 2];
            float4 P = make_float4(x, y, z, fmaf(x, x, fmaf(y, y, z * z)));
            int c = cell_of(x, y, z);
            int slot = atomicAdd(&cellcnt[c], 1);
            if (slot < SLOTS) {
                pos4s[c * SLOTS + slot] = P;
                origidx[c * SLOTS + slot] = i;
            } else {
                int o = atomicAdd(&cellcnt[4096], 1);   // overflow count
                if (o < OCAP) { ovfpos[o] = P; ovfidx[o] = i; }
            }
        }
    }
}

// ---- fused: cell-count tau -> phase1 exact tau* -> phase2 -> top-32 ->
//      embed -> MFMA GEMM1 -> gelu/mean -> W2 matvec -> featsM ----
__global__ __launch_bounds__(256, 4)
void fused_knn_mlp(const float* __restrict__ pos,
                   const float4* __restrict__ pos4s,
                   const int* __restrict__ origidx,
                   const int* __restrict__ cellcnt,
                   const int* __restrict__ ovfidx, const float4* __restrict__ ovfpos,
                   const int* __restrict__ supidx,
                   const ushort* __restrict__ W1t, const float* __restrict__ b1,
                   const float* __restrict__ W2, const float* __restrict__ b2,
                   float* __restrict__ featsM)
{
    // 16 KB pool, time-multiplexed:
    //  select: amaxd[128]@0 | acnt[128]@512 | ccell[256]@1024 | ccnt[256]@2048 |
    //          cmnd[256]@3072 | cpre[256]@4096 | d2buf[512]@5120 | obuf[512]@7168
    //  mlp:    msg bf16[32][256]@0 (16 KB, XOR-swizzled)  then p2 f32[1024]@0
    __shared__ __align__(16) char pool[16384];
    float* amaxd = (float*)pool;
    int*   acnt  = (int*)(pool + 512);
    int*   ccell = (int*)(pool + 1024);
    int*   ccnt  = (int*)(pool + 2048);
    float* cmnd  = (float*)(pool + 3072);
    int*   cpre  = (int*)(pool + 4096);
    float* d2buf = (float*)(pool + 5120);
    int*   obuf  = (int*)(pool + 7168);
    ushort* msg  = (ushort*)pool;
    float*  p2   = (float*)pool;

    __shared__ float rf[KNB][5];
    __shared__ int   selo[KNB];
    __shared__ float hb[H];
    __shared__ int   wsum[4];
    __shared__ float tau2_sh, tau32_sh;
    __shared__ int   cnt_sh, ncl;

    const int s    = blockIdx.x;
    const int t    = threadIdx.x;
    const int lane = t & 63;
    const int w    = t >> 6;

    const int sidx = supidx[s];
    const float sx = pos[3 * sidx], sy = pos[3 * sidx + 1], sz = pos[3 * sidx + 2];

    constexpr float L2_10000 = 13.287712379549449f;

    // supernode abs-pos embed -> featsM[s][0..255]
    {
        float se = 0.f;
        if (t < 252) {
            int c  = t / 84;
            int rr = t - c * 84;
            int f  = (rr < 42) ? rr : rr - 42;
            float coord = (c == 0) ? sx : ((c == 1) ? sy : sz);
            float ang = coord * exp2f(-(float)f * (L2_10000 / 42.f));
            se = (rr < 42) ? __sinf(ang) : __cosf(ang);
        }
        featsM[s * (2 * H) + t] = se;
    }
    if (t == 0) { ncl = 0; tau2_sh = 301.f; }

    // ---- stage A: tau_cells from 5^3 cell counts (no point loads) ----
    const int scx = min(GC - 1, max(0, (int)(sx * HINV)));
    const int scy = min(GC - 1, max(0, (int)(sy * HINV)));
    const int scz = min(GC - 1, max(0, (int)(sz * HINV)));
    const int ax0 = max(0, scx - 2), ax1 = min(GC - 1, scx + 2);
    const int ay0 = max(0, scy - 2), ay1 = min(GC - 1, scy + 2);
    const int az0 = max(0, scz - 2), az1 = min(GC - 1, scz + 2);
    const int anx = ax1 - ax0 + 1, any_ = ay1 - ay0 + 1, anz = az1 - az0 + 1;
    const int an  = anx * any_ * anz;    // <= 125
    __syncthreads();
    for (int ci = t; ci < an; ci += 256) {
        int X = ax0 + ci % anx, rem = ci / anx;
        int Y = ay0 + rem % any_, Z = az0 + rem / any_;
        int cell = (Z * GC + Y) * GC + X;
        acnt[ci] = min(cellcnt[cell], SLOTS);
        float lx = X * HCEL, ly = Y * HCEL, lz = Z * HCEL;
        float mx = fmaxf(fabsf(sx - lx), fabsf(lx + HCEL - sx));
        float my = fmaxf(fabsf(sy - ly), fabsf(ly + HCEL - sy));
        float mz = fmaxf(fabsf(sz - lz), fabsf(lz + HCEL - sz));
        amaxd[ci] = mx * mx + my * my + mz * mz;
    }
    __syncthreads();
    for (int ci = t; ci < an; ci += 256) {
        float myv = amaxd[ci];
        int S = 0;
        for (int j = 0; j < an; j++) {
            bool less = (amaxd[j] < myv) || (amaxd[j] == myv && j < ci);
            S += less ? acnt[j] : 0;
        }
        if (S < KNB && KNB <= S + acnt[ci]) tau2_sh = myv;
    }
    __syncthreads();
    const float tau2 = tau2_sh;
    const float R2 = tau2 + 1e-3f;
    const float R  = sqrtf(R2);
    if (t == 0) tau32_sh = R2;   // fallback if phase1 < 32

    // ---- stage B: enumerate ball cells (cell, cnt|p1flag, mind2) ----
    const int bx0 = max(0, (int)floorf((sx - R) * HINV));
    const int bx1 = min(GC - 1, (int)floorf((sx + R) * HINV));
    const int by0 = max(0, (int)floorf((sy - R) * HINV));
    const int by1 = min(GC - 1, (int)floorf((sy + R) * HINV));
    const int bz0 = max(0, (int)floorf((sz - R) * HINV));
    const int bz1 = min(GC - 1, (int)floorf((sz + R) * HINV));
    const int nbx = bx1 - bx0 + 1, nby = by1 - by0 + 1, nbz = bz1 - bz0 + 1;
    const int ncb = nbx * nby * nbz;
    for (int ci = t; ci < ncb; ci += 256) {
        int X = bx0 + ci % nbx, rem = ci / nbx;
        int Y = by0 + rem % nby, Z = bz0 + rem / nby;
        float lx = X * HCEL, ly = Y * HCEL, lz = Z * HCEL;
        float ddx = fmaxf(fmaxf(lx - sx, sx - (lx + HCEL)), 0.f);
        float ddy = fmaxf(fmaxf(ly - sy, sy - (ly + HCEL)), 0.f);
        float ddz = fmaxf(fmaxf(lz - sz, sz - (lz + HCEL)), 0.f);
        float mnd = ddx * ddx + ddy * ddy + ddz * ddz;
        if (mnd > R2) continue;
        int cell = (Z * GC + Y) * GC + X;
        int cn = min(cellcnt[cell], SLOTS);
        if (cn == 0) continue;
        // amaxd, same expression as stage A (bitwise-identical)
        float mx = fmaxf(fabsf(sx - lx), fabsf(lx + HCEL - sx));
        float my = fmaxf(fabsf(sy - ly), fabsf(ly + HCEL - sy));
        float mz = fmaxf(fabsf(sz - lz), fabsf(lz + HCEL - sz));
        float amx = mx * mx + my * my + mz * mz;
        int p1 = (amx <= tau2) ? 1 : 0;
        int sl = atomicAdd(&ncl, 1);
        if (sl < 256) { ccell[sl] = cell; ccnt[sl] = cn | (p1 << 8); cmnd[sl] = mnd; }
    }
    __syncthreads();
    const int nclc = min(ncl, 256);

    // shuffle-based inclusive prefix over 256 masked counts (2 barriers)
    auto build_prefix = [&](int phase, float tlim) -> int {
        int v = 0;
        if (t < nclc) {
            int cc = ccnt[t];
            int cn = cc & 0xff;
            int p1 = cc >> 8;
            v = (phase == 1) ? (p1 ? cn : 0)
                             : ((!p1 && cmnd[t] <= tlim) ? cn : 0);
        }
#pragma unroll
        for (int off = 1; off < 64; off <<= 1) {
            int x = __shfl_up(v, off);
            if (lane >= off) v += x;
        }
        if (lane == 63) wsum[w] = v;
        __syncthreads();
        int add = 0;
#pragma unroll
        for (int j = 0; j < 4; j++) if (j < w) add += wsum[j];
        v += add;
        cpre[t] = v;
        __syncthreads();
        return cpre[255];
    };
    auto bsearch = [&](int j) -> int {
        int lo = 0;
#pragma unroll
        for (int st = 128; st; st >>= 1) {
            int nlo = lo + st;
            if (nlo <= 256 && cpre[nlo - 1] <= j) lo = nlo;
        }
        return lo;
    };

    // ---- phase 1: gather ALL points of P1 cells (dense, no atomics) ----
    const int tot1 = build_prefix(1, 0.f);
    const int M1 = min(tot1, CAP);
    for (int j0 = 0; j0 < M1; j0 += 256) {
        int j = j0 + t;
        if (j < M1) {
            int lo = bsearch(j);
            int off = j - (lo ? cpre[lo - 1] : 0);
            int u = ccell[lo] * SLOTS + off;
            float4 P = pos4s[u];
            float dx = sx - P.x, dy = sy - P.y, dz = sz - P.z;
            d2buf[j] = dx * dx + dy * dy + dz * dz;
            obuf[j]  = origidx[u];
        }
    }
    const int Mp1 = (M1 + 3) & ~3;
    for (int u = M1 + t; u < Mp1; u += 256) { d2buf[u] = INFINITY; obuf[u] = 0x7fffffff; }
    if (t == 0) cnt_sh = M1;
    __syncthreads();

    // exact 32nd-smallest of phase-1 set -> tau* (<= tau2 by construction)
    for (int u = t; u < M1; u += 256) {
        float myv = d2buf[u];
        int   myo = obuf[u];
        int rank = 0;
        for (int v2 = 0; v2 < Mp1; v2 += 4) {
            float4 dv = *(const float4*)&d2buf[v2];
            int4   iv = *(const int4*)&obuf[v2];
            rank += (dv.x < myv) || (dv.x == myv && iv.x < myo);
            rank += (dv.y < myv) || (dv.y == myv && iv.y < myo);
            rank += (dv.z < myv) || (dv.z == myv && iv.z < myo);
            rank += (dv.w < myv) || (dv.w == myv && iv.w < myo);
        }
        if (rank == KNB - 1) tau32_sh = myv;
    }
    __syncthreads();
    const float tau32 = tau32_sh;

    // ---- phase 2: cells with mind2 <= tau*, filter d2 <= tau* ----
    const int tot2 = build_prefix(2, tau32);
    for (int j0 = 0; j0 < tot2; j0 += 256) {
        int j = j0 + t;
        bool pass = false; float pd2 = 0.f; int po = 0;
        if (j < tot2) {
            int lo = bsearch(j);
            int off = j - (lo ? cpre[lo - 1] : 0);
            int u = ccell[lo] * SLOTS + off;
            float4 P = pos4s[u];
            float dx = sx - P.x, dy = sy - P.y, dz = sz - P.z;
            pd2 = dx * dx + dy * dy + dz * dz;
            if (pd2 <= tau32) { pass = true; po = origidx[u]; }
        }
        unsigned long long m = __ballot(pass);
        if (m) {
            int ldr = __ffsll(m) - 1;
            int base = 0;
            if (lane == ldr) base = atomicAdd(&cnt_sh, __popcll(m));
            base = __shfl(base, ldr);
            if (pass) {
                int slp = base + __popcll(m & ((1ull << lane) - 1ull));
                if (slp < CAP) { d2buf[slp] = pd2; obuf[slp] = po; }
            }
        }
    }
    // overflow spill list (expected empty)
    {
        int no = min(cellcnt[4096], OCAP);
        for (int j = t; j < no; j += 256) {
            float4 P = ovfpos[j];
            float dx = sx - P.x, dy = sy - P.y, dz = sz - P.z;
            float pd2 = dx * dx + dy * dy + dz * dz;
            if (pd2 <= tau32) {
                int slp = atomicAdd(&cnt_sh, 1);
                if (slp < CAP) { d2buf[slp] = pd2; obuf[slp] = ovfidx[j]; }
            }
        }
    }
    __syncthreads();
    const int M = min(cnt_sh, CAP);
    const int Mpad = (M + 3) & ~3;
    for (int u = M + t; u < Mpad; u += 256) { d2buf[u] = INFINITY; obuf[u] = 0x7fffffff; }
    __syncthreads();

    // final exact rank-merge -> top-32
    for (int u = t; u < M; u += 256) {
        float myv = d2buf[u];
        int   myo = obuf[u];
        int rank = 0;
        for (int v2 = 0; v2 < Mpad; v2 += 4) {
            float4 dv = *(const float4*)&d2buf[v2];
            int4   iv = *(const int4*)&obuf[v2];
            rank += (dv.x < myv) || (dv.x == myv && iv.x < myo);
            rank += (dv.y < myv) || (dv.y == myv && iv.y < myo);
            rank += (dv.z < myv) || (dv.z == myv && iv.z < myo);
            rank += (dv.w < myv) || (dv.w == myv && iv.w < myo);
        }
        if (rank < KNB) selo[rank] = myo;
    }
    __syncthreads();
    if (t < KNB) {
        int ni = selo[t];
        float px = pos[3 * ni], py = pos[3 * ni + 1], pz = pos[3 * ni + 2];
        float rx = sx - px, ry = sy - py, rz = sz - pz;
        float dd = sqrtf(rx * rx + ry * ry + rz * rz);
        rf[t][0] = rx; rf[t][1] = ry; rf[t][2] = rz; rf[t][3] = dd;
    }
    __syncthreads();   // select stage dead; msg takes pool

    // ---- sincos embed -> msg[k][i] bf16, row-XOR swizzle ----
#pragma unroll
    for (int n = 0; n < 16; n++) {
        int item = t + n * 256;
        int f = item & 31;
        int c = (item >> 5) & 3;
        int k = item >> 7;
        float ang = rf[k][c] * exp2f(-(float)f * (L2_10000 / 32.f));
        int swz = (k & 7) << 3;
        msg[((k << 8) | (c * 64 + f))      ^ swz] = f2bf(__sinf(ang));
        msg[((k << 8) | (c * 64 + 32 + f)) ^ swz] = f2bf(__cosf(ang));
    }
    __syncthreads();

    // ---- MFMA GEMM1: wave w owns j-rows [64w, 64w+64) ----
    {
        const int lr = lane & 15;
        const int lg = lane >> 4;
        f32x4 acc[4][2];
#pragma unroll
        for (int mt = 0; mt < 4; mt++)
#pragma unroll
            for (int nt = 0; nt < 2; nt++) acc[mt][nt] = (f32x4){0, 0, 0, 0};
#pragma unroll
        for (int kk = 0; kk < 8; kk++) {
            const int i0 = kk * 32 + lg * 8;
            const int swz = (lr & 7) << 3;
            bf16x8 b0  = *(const bf16x8*)(msg + ((( lr       << 8) | i0) ^ swz));
            bf16x8 b1v = *(const bf16x8*)(msg + ((((lr + 16) << 8) | i0) ^ swz));
#pragma unroll
            for (int mt = 0; mt < 4; mt++) {
                bf16x8 a = *(const bf16x8*)(W1t + ((64 * w + 16 * mt + lr) << 8) + i0);
                acc[mt][0] = __builtin_amdgcn_mfma_f32_16x16x32_bf16(a, b0,  acc[mt][0], 0, 0, 0);
                acc[mt][1] = __builtin_amdgcn_mfma_f32_16x16x32_bf16(a, b1v, acc[mt][1], 0, 0, 0);
            }
        }
        float part[16];
#pragma unroll
        for (int mt = 0; mt < 4; mt++)
#pragma unroll
            for (int r = 0; r < 4; r++) {
                int j = 64 * w + 16 * mt + 4 * lg + r;
                float bj = b1[j];
                part[mt * 4 + r] = gelu_fast(acc[mt][0][r] + bj) + gelu_fast(acc[mt][1][r] + bj);
            }
#pragma unroll
        for (int off = 1; off < 16; off <<= 1)
#pragma unroll
            for (int u = 0; u < 16; u++)
                part[u] += __shfl_xor(part[u], off);
        if (lr == 0) {
#pragma unroll
            for (int u = 0; u < 16; u++) {
                int mt = u >> 2, r = u & 3;
                hb[64 * w + 16 * mt + 4 * lg + r] = part[u] * (1.0f / 32.0f);
            }
        }
    }
    __syncthreads();   // hb ready; msg dead -> p2

    // ---- W2 matvec: agg = hb @ W2 + b2 -> featsM[s][256..511] ----
    {
        const int g  = t >> 6;
        const int j4 = (t & 63) * 4;
        const int ib = g * 64;
        float4 a = {0.f, 0.f, 0.f, 0.f};
        for (int i = 0; i < 64; i++) {
            float hv = hb[ib + i];
            float4 wv = *(const float4*)&W2[(ib + i) * H + j4];
            a.x = fmaf(hv, wv.x, a.x); a.y = fmaf(hv, wv.y, a.y);
            a.z = fmaf(hv, wv.z, a.z); a.w = fmaf(hv, wv.w, a.w);
        }
        *(float4*)&p2[g * 256 + j4] = a;
    }
    __syncthreads();
    {
        float agg = p2[t] + p2[256 + t] + p2[512 + t] + p2[768 + t] + b2[t];
        featsM[s * (2 * H) + H + t] = agg;
    }
}

// ---- kernel B: C[M x N] = A[M x K] @ B[K x N] + bias, fp32 tiled 32x32 ----
__global__ __launch_bounds__(256)
void gemm_bias(const float* __restrict__ A, const float* __restrict__ B,
               const float* __restrict__ bias, float* __restrict__ C,
               int K, int N, int ldc)
{
    __shared__ float As[32][36];
    __shared__ float Bs[32][36];
    const int t  = threadIdx.x;
    const int bm = blockIdx.x, bn = blockIdx.y;
    const int tx = t & 15, ty = t >> 4;
    const int lr = t >> 3, lc = (t & 7) * 4;

    float acc[2][2] = {{0.f, 0.f}, {0.f, 0.f}};

    for (int kk = 0; kk < K; kk += 32) {
        float4 av = *(const float4*)&A[(bm * 32 + lr) * K + kk + lc];
        float4 bv = *(const float4*)&B[(kk + lr) * N + bn * 32 + lc];
        *(float4*)&As[lr][lc] = av;
        *(float4*)&Bs[lr][lc] = bv;
        __syncthreads();
#pragma unroll
        for (int k = 0; k < 32; k++) {
            float a0 = As[2 * ty][k], a1 = As[2 * ty + 1][k];
            float2 b01 = *(const float2*)&Bs[k][2 * tx];
            acc[0][0] += a0 * b01.x; acc[0][1] += a0 * b01.y;
            acc[1][0] += a1 * b01.x; acc[1][1] += a1 * b01.y;
        }
        __syncthreads();
    }
#pragma unroll
    for (int u = 0; u < 2; u++) {
        int row = bm * 32 + 2 * ty + u;
        int col = bn * 32 + 2 * tx;
        C[row * ldc + col]     = acc[u][0] + bias[col];
        C[row * ldc + col + 1] = acc[u][1] + bias[col + 1];
    }
}

extern "C" void kernel_launch(void* const* d_in, const int* in_sizes, int n_in,
                              void* d_out, int out_size, void* d_ws, size_t ws_size,
                              hipStream_t stream) {
    const float* pos = (const float*)d_in[0];
    const int*   sup = (const int*)d_in[1];
    const float* W1  = (const float*)d_in[2];
    const float* b1  = (const float*)d_in[3];
    const float* W2  = (const float*)d_in[4];
    const float* b2  = (const float*)d_in[5];
    const float* Wp  = (const float*)d_in[6];
    const float* bp  = (const float*)d_in[7];

    const int N = in_sizes[0] / 3;
    const int S = in_sizes[1];
    float* out = (float*)d_out;

    char* ws = (char*)d_ws;
    ushort* W1t     = (ushort*)ws;                      // 128 KB
    float4* pos4s   = (float4*)(ws + (128 << 10));      // 4096*32*16 = 2 MB
    int*    origidx = (int*)(ws + (2176 << 10));        // 512 KB
    int*    cellcnt = (int*)(ws + (2688 << 10));        // 4097 ints
    int*    ovfidx  = (int*)(ws + (2708 << 10));        // 1 KB
    float4* ovfpos  = (float4*)(ws + (2712 << 10));     // 4 KB
    float*  featsM  = (float*)(ws + (2720 << 10));      // 2 MB

    hipMemsetAsync(cellcnt, 0, 4097 * sizeof(int), stream);
    prep<<<64 + (N + 255) / 256, 256, 0, stream>>>(W1, pos, N, W1t, pos4s,
                                                   origidx, cellcnt, ovfidx, ovfpos);
    fused_knn_mlp<<<S, 256, 0, stream>>>(pos, pos4s, origidx, cellcnt,
                                         ovfidx, ovfpos, sup,
                                         W1t, b1, W2, b2, featsM);
    gemm_bias<<<dim3(S / 32, H / 32), 256, 0, stream>>>(featsM, Wp, bp, out,
                                                        2 * H, H, H);
}